// Round 9
// baseline (368.550 us; speedup 1.0000x reference)
//
#include <hip/hip_runtime.h>
#include <math.h>
#include <stdint.h>

#define B_    2
#define S_    1024
#define D_    1024
#define H_    16
#define DH_   64
#define KTOP_ 8
#define NN_   64
#define NB_   32
#define R_    64
#define DFF_  4096
#define M_    (B_*S_)   // 2048 tokens

typedef unsigned short ushortT;
typedef short bf16x8 __attribute__((ext_vector_type(8)));
typedef float f32x4 __attribute__((ext_vector_type(4)));

// ---------------- helpers ----------------
__device__ __forceinline__ float wredsum(float v){
  #pragma unroll
  for(int o=32;o;o>>=1) v += __shfl_xor(v,o,64);
  return v;
}
__device__ __forceinline__ float gelu_f(float t){
  return 0.5f*t*(1.f+erff(t*0.70710678118654752440f));
}
__device__ __forceinline__ ushortT f2bf(float f){
  unsigned u = __float_as_uint(f);
  unsigned r = (u + 0x7FFFu + ((u>>16)&1u)) >> 16;
  return (ushortT)r;
}
__device__ __forceinline__ float bf2f(ushortT u){
  return __uint_as_float(((unsigned)u)<<16);
}
__device__ __forceinline__ void gload_lds16(const void* g, void* l){
  __builtin_amdgcn_global_load_lds(
    (const __attribute__((address_space(1))) unsigned int*)(uintptr_t)g,
    (__attribute__((address_space(3))) unsigned int*)(uintptr_t)l,
    16, 0, 0);
}
template<int N> __device__ __forceinline__ void waitcnt_vm(){
  asm volatile("s_waitcnt vmcnt(%0)" :: "n"(N) : "memory");
}

// ---------------- tiny kernels ----------------
__global__ void k_softmax_recipe(const float* __restrict__ rec, float* __restrict__ P){
  int r = threadIdx.x; // 0..63
  float v[NB_]; float mx = -3.4e38f;
  #pragma unroll
  for(int j=0;j<NB_;j++){ v[j]=rec[r*NB_+j]; mx=fmaxf(mx,v[j]); }
  float s=0.f;
  #pragma unroll
  for(int j=0;j<NB_;j++){ v[j]=expf(v[j]-mx); s+=v[j]; }
  float inv=1.f/s;
  #pragma unroll
  for(int j=0;j<NB_;j++) P[r*NB_+j]=v[j]*inv;
}

// neuron_emb (bf16) + sbias[n] = emb[n]·bs
__global__ __launch_bounds__(256) void k_neuron_emb(const float* __restrict__ P,
    const float* __restrict__ bemb, const float* __restrict__ bs,
    ushortT* __restrict__ embb, float* __restrict__ sbias){
  int n = blockIdx.x;
  __shared__ float p[NB_];
  __shared__ float red[4];
  if(threadIdx.x<NB_) p[threadIdx.x]=P[n*NB_+threadIdx.x];
  __syncthreads();
  int d = threadIdx.x*4;
  float4 acc = {0,0,0,0};
  #pragma unroll
  for(int j=0;j<NB_;j++){
    float4 b = *(const float4*)&bemb[j*D_+d];
    float pj = p[j];
    acc.x += pj*b.x; acc.y += pj*b.y; acc.z += pj*b.z; acc.w += pj*b.w;
  }
  uint2 pk;
  pk.x = (unsigned)f2bf(acc.x) | ((unsigned)f2bf(acc.y)<<16);
  pk.y = (unsigned)f2bf(acc.z) | ((unsigned)f2bf(acc.w)<<16);
  *(uint2*)&embb[n*D_+d] = pk;
  float4 b4 = *(const float4*)&bs[d];
  float part = acc.x*b4.x + acc.y*b4.y + acc.z*b4.z + acc.w*b4.w;
  part = wredsum(part);
  int w = threadIdx.x>>6, lane = threadIdx.x&63;
  if(lane==0) red[w]=part;
  __syncthreads();
  if(threadIdx.x==0) sbias[n]=red[0]+red[1]+red[2]+red[3];
}

// dual layernorm -> acb cols [0,1024) bf16 (xn1), xn2b bf16
__global__ __launch_bounds__(256) void k_ln_dual(const float* __restrict__ x,
    const float* __restrict__ g1,const float* __restrict__ b1,
    const float* __restrict__ g2,const float* __restrict__ b2,
    ushortT* __restrict__ acb, ushortT* __restrict__ xn2b){
  int m = blockIdx.x;
  const float* xr = x + (size_t)m*D_;
  int d = threadIdx.x*4;
  float4 xv = *(const float4*)&xr[d];
  float s  = xv.x+xv.y+xv.z+xv.w;
  float ss = xv.x*xv.x+xv.y*xv.y+xv.z*xv.z+xv.w*xv.w;
  s = wredsum(s); ss = wredsum(ss);
  __shared__ float sh[8];
  int w = threadIdx.x>>6, lane = threadIdx.x&63;
  if(lane==0){ sh[w]=s; sh[4+w]=ss; }
  __syncthreads();
  s  = sh[0]+sh[1]+sh[2]+sh[3];
  ss = sh[4]+sh[5]+sh[6]+sh[7];
  float mu  = s*(1.f/(float)D_);
  float var = ss*(1.f/(float)D_) - mu*mu;
  float rstd = rsqrtf(var + 1e-5f);
  float4 ga = *(const float4*)&g1[d]; float4 ba = *(const float4*)&b1[d];
  float4 gb = *(const float4*)&g2[d]; float4 bb = *(const float4*)&b2[d];
  float n0=(xv.x-mu)*rstd, n1=(xv.y-mu)*rstd, n2=(xv.z-mu)*rstd, n3=(xv.w-mu)*rstd;
  float o10=n0*ga.x+ba.x, o11=n1*ga.y+ba.y, o12=n2*ga.z+ba.z, o13=n3*ga.w+ba.w;
  float o20=n0*gb.x+bb.x, o21=n1*gb.y+bb.y, o22=n2*gb.z+bb.z, o23=n3*gb.w+bb.w;
  uint2 p1; p1.x = (unsigned)f2bf(o10) | ((unsigned)f2bf(o11)<<16);
  p1.y = (unsigned)f2bf(o12) | ((unsigned)f2bf(o13)<<16);
  *(uint2*)&acb[(size_t)m*2048 + d] = p1;
  uint2 p2; p2.x = (unsigned)f2bf(o20) | ((unsigned)f2bf(o21)<<16);
  p2.y = (unsigned)f2bf(o22) | ((unsigned)f2bf(o23)<<16);
  *(uint2*)&xn2b[(size_t)m*D_ + d] = p2;
}

// fp32 W[K][N] -> bf16 Wt[N][K]
__global__ __launch_bounds__(256) void k_cvt_wt(const float* __restrict__ W,
    ushortT* __restrict__ Wt, int K, int N){
  __shared__ float t[32][33];
  int nt = blockIdx.x*32, kt = blockIdx.y*32;
  int r = threadIdx.x>>3, c4 = (threadIdx.x&7)*4;
  float4 v = *(const float4*)&W[(size_t)(kt+r)*N + nt + c4];
  t[r][c4+0]=v.x; t[r][c4+1]=v.y; t[r][c4+2]=v.z; t[r][c4+3]=v.w;
  __syncthreads();
  uint2 p;
  p.x = (unsigned)f2bf(t[c4+0][r]) | ((unsigned)f2bf(t[c4+1][r])<<16);
  p.y = (unsigned)f2bf(t[c4+2][r]) | ((unsigned)f2bf(t[c4+3][r])<<16);
  *(uint2*)&Wt[(size_t)(nt+r)*K + kt + c4] = p;
}

// straight fp32 -> bf16 (4 elems/thread)
__global__ void k_cvt_str(const float* __restrict__ W, ushortT* __restrict__ O){
  int i = (blockIdx.x*256 + threadIdx.x)*4;
  float4 v = *(const float4*)&W[i];
  uint2 p;
  p.x = (unsigned)f2bf(v.x) | ((unsigned)f2bf(v.y)<<16);
  p.y = (unsigned)f2bf(v.z) | ((unsigned)f2bf(v.w)<<16);
  *(uint2*)&O[i] = p;
}

// fused Q/K/V weight convert (all 1024x1024) via blockIdx.z
__global__ __launch_bounds__(256) void k_cvt_qkv(const float* __restrict__ wq,
    const float* __restrict__ wk, const float* __restrict__ wv,
    ushortT* __restrict__ Wt){
  __shared__ float t[32][33];
  const float* W = (blockIdx.z==0)?wq:(blockIdx.z==1)?wk:wv;
  ushortT* O = Wt + (size_t)blockIdx.z*1048576;
  int nt = blockIdx.x*32, kt = blockIdx.y*32;
  int r = threadIdx.x>>3, c4 = (threadIdx.x&7)*4;
  float4 v = *(const float4*)&W[(size_t)(kt+r)*1024 + nt + c4];
  t[r][c4+0]=v.x; t[r][c4+1]=v.y; t[r][c4+2]=v.z; t[r][c4+3]=v.w;
  __syncthreads();
  uint2 p;
  p.x = (unsigned)f2bf(t[c4+0][r]) | ((unsigned)f2bf(t[c4+1][r])<<16);
  p.y = (unsigned)f2bf(t[c4+2][r]) | ((unsigned)f2bf(t[c4+3][r])<<16);
  *(uint2*)&O[(size_t)(nt+r)*1024 + kt + c4] = p;
}

__global__ void k_cat3(const float* __restrict__ a, const float* __restrict__ b,
                       const float* __restrict__ c, float* __restrict__ o){
  int i = blockIdx.x*256 + threadIdx.x;
  if(i>=3072) return;
  o[i] = (i<1024)? a[i] : (i<2048)? b[i-1024] : c[i-2048];
}

// basis_A [32][1024][64] fp32 -> Abnr[(n*64+r)][d] bf16 + Abdnr[d][n*64+r] bf16
__global__ __launch_bounds__(256) void k_cvt_basis(const float* __restrict__ bA,
    ushortT* __restrict__ Abnr, ushortT* __restrict__ Abdnr){
  __shared__ float t[32][33];
  int dt = blockIdx.x*32, rt = blockIdx.y*32, n = blockIdx.z;
  int i = threadIdx.x>>3, j4 = (threadIdx.x&7)*4;
  float4 v = *(const float4*)&bA[((size_t)n<<16) + (size_t)(dt+i)*64 + rt + j4];
  t[i][j4+0]=v.x; t[i][j4+1]=v.y; t[i][j4+2]=v.z; t[i][j4+3]=v.w;
  uint2 pd;
  pd.x = (unsigned)f2bf(v.x) | ((unsigned)f2bf(v.y)<<16);
  pd.y = (unsigned)f2bf(v.z) | ((unsigned)f2bf(v.w)<<16);
  *(uint2*)&Abdnr[(size_t)(dt+i)*2048 + n*64 + rt + j4] = pd;
  __syncthreads();
  uint2 p;
  p.x = (unsigned)f2bf(t[j4+0][i]) | ((unsigned)f2bf(t[j4+1][i])<<16);
  p.y = (unsigned)f2bf(t[j4+2][i]) | ((unsigned)f2bf(t[j4+3][i])<<16);
  *(uint2*)&Abnr[(size_t)(n*64+rt+i)*1024 + dt + j4] = p;
}

// ------- MFMA GEMM, counted-vmcnt 2-phase pipeline, BK=64, XOR-swizzled LDS,
//         XCD-aware block swizzle (all grids are %8==0) ----------------------
// C[M,N] = A[M,K](bf16) @ Wt[N,K]^T
// OUT: 0 f32, 1 bf16, 2 QKV-scatter
// EPI: 0 +bias | 1 +bias,gelu | 2 +bias,+res(f32) | 3 bf16res + alpha (no bias)
template<int BM,int BN,int OUT,int EPI>
__global__ __launch_bounds__(256) void k_mgemm(
    const ushortT* __restrict__ A, int lda, int K,
    const ushortT* __restrict__ Wt,
    void* __restrict__ Cout, int N,
    const float* __restrict__ bias, const float* __restrict__ res,
    const ushortT* __restrict__ res16, const float* __restrict__ alphaP,
    ushortT* __restrict__ qkv){
  constexpr int MR  = (BM==128 && BN==128)?4:2;
  constexpr int NR  = (BM==64  && BN==64 )?2:4;
  constexpr int ACH = BM/32;
  constexpr int BCH = BN/32;
  constexpr int NLD = ACH + BCH;   // global_load_lds per thread per stage
  __shared__ __align__(16) ushortT As[2][BM*64];
  __shared__ __align__(16) ushortT Bs[2][BN*64];
  const int tid = threadIdx.x;
  const int w = tid>>6, l = tid&63;
  // XCD swizzle: hardware flat id -> contiguous work chunk per XCD
  int hflat = blockIdx.y*gridDim.x + blockIdx.x;
  int cpx = (gridDim.x*gridDim.y)>>3;
  int wflat = (hflat&7)*cpx + (hflat>>3);
  const int bx = wflat % gridDim.x, by = wflat / gridDim.x;
  const int row0 = by*BM, col0 = bx*BN;
  const int lr = l>>3, lsw = (l&7)^lr;
  const int fr = l&15, fs = l>>4;
  const int WR = (BM==128&&BN==128)?((w>>1)*64):(BM==128)?(w*32):((w>>1)*32);
  const int WC = (BM==128&&BN==128)?((w&1)*64):(BM==128)?0:((w&1)*32);
  f32x4 acc[MR][NR];
  #pragma unroll
  for(int m=0;m<MR;m++)
    #pragma unroll
    for(int n=0;n<NR;n++)
      #pragma unroll
      for(int e=0;e<4;e++) acc[m][n][e]=0.f;
  const ushortT* Ag = A  + (size_t)(row0 + w*(BM/4) + lr)*lda + (lsw<<3);
  const ushortT* Bg = Wt + (size_t)(col0 + w*(BN/4) + lr)*K   + (lsw<<3);
  auto stage=[&](int buf,int k0){
    #pragma unroll
    for(int c=0;c<ACH;c++)
      gload_lds16(Ag + (size_t)(c*8)*lda + k0, &As[buf][(w*(BM/4)+c*8)*64]);
    #pragma unroll
    for(int c=0;c<BCH;c++)
      gload_lds16(Bg + (size_t)(c*8)*K + k0, &Bs[buf][(w*(BN/4)+c*8)*64]);
  };
  stage(0,0);
  const int NT = K>>6;
  for(int t=0;t<NT;t++){
    const int cur = t&1;
    if(t+1<NT){
      stage(cur^1,(t+1)<<6);
      waitcnt_vm<NLD>();
    } else {
      waitcnt_vm<0>();
    }
    __builtin_amdgcn_s_barrier();
    __builtin_amdgcn_sched_barrier(0);
    #pragma unroll
    for(int kc=0;kc<2;kc++){
      bf16x8 af[MR], bv[NR];
      #pragma unroll
      for(int m=0;m<MR;m++){
        int r_ = WR + m*16 + fr;
        af[m] = *(const bf16x8*)&As[cur][(r_*64 + (kc*4+fs)*8) ^ ((r_&7)<<3)];
      }
      #pragma unroll
      for(int n=0;n<NR;n++){
        int r_ = WC + n*16 + fr;
        bv[n] = *(const bf16x8*)&Bs[cur][(r_*64 + (kc*4+fs)*8) ^ ((r_&7)<<3)];
      }
      #pragma unroll
      for(int m=0;m<MR;m++)
        #pragma unroll
        for(int n=0;n<NR;n++)
          acc[m][n] = __builtin_amdgcn_mfma_f32_16x16x32_bf16(af[m], bv[n], acc[m][n], 0,0,0);
    }
    __builtin_amdgcn_s_barrier();
  }
  #pragma unroll
  for(int m=0;m<MR;m++){
    #pragma unroll
    for(int n=0;n<NR;n++){
      #pragma unroll
      for(int r=0;r<4;r++){
        int row = row0 + WR + m*16 + fs*4 + r;
        int col = col0 + WC + n*16 + fr;
        float v = acc[m][n][r];
        if(EPI!=3 && bias) v += bias[col];
        if(EPI==1) v = gelu_f(v);
        if(EPI==2) v += res[(size_t)row*N + col];
        if(EPI==3) v = bf2f(res16[(size_t)row*N + col]) + alphaP[0]*v;
        if(OUT==0){ ((float*)Cout)[(size_t)row*N + col] = v; }
        else if(OUT==1){ ((ushortT*)Cout)[(size_t)row*N + col] = f2bf(v); }
        else {
          int part = col>>10, cc = col&1023, hh = cc>>6, dh = cc&63;
          int bb = row>>10, s = row&1023;
          if(part==0)      qkv[            ((size_t)(bb*16+hh)*1024 + s)*64 + dh] = f2bf(v);
          else if(part==1) qkv[2097152u + (((size_t)(bb*16+hh)*1024 + s)*64 + dh)] = f2bf(v);
          else             qkv[4194304u + (((size_t)(bb*16+hh)*64 + dh)*1024 + s)] = f2bf(v);
        }
      }
    }
  }
}

// ---- MFMA attention: LDS-shared K/V (64-key tiles), counted-vmcnt pipeline --
__global__ __launch_bounds__(256) void k_mha(const ushortT* __restrict__ Qh,
    const ushortT* __restrict__ Kh, const ushortT* __restrict__ Vt,
    float* __restrict__ Opart, float* __restrict__ Lpart){
  __shared__ __align__(16) ushortT Ks[2][64*64];
  __shared__ __align__(16) ushortT Vs[2][64*64];
  __shared__ __align__(16) ushortT Plds[4][16][72];
  const int l = threadIdx.x & 63, w = threadIdx.x >> 6;
  const int qt = blockIdx.x, h = blockIdx.y, zz = blockIdx.z;
  const int b = zz>>1, ks = zz&1;
  const int bh = b*H_ + h;
  const ushortT* Qb = Qh + (size_t)bh*65536;
  const ushortT* Kb = Kh + (size_t)bh*65536 + (size_t)ks*512*64;
  const ushortT* Vb = Vt + (size_t)bh*65536 + (size_t)ks*512;
  float* Op = Opart + ((size_t)(ks*32+bh))*65536;
  float* Lp = Lpart + ((size_t)(ks*32+bh))*1024;
  const int q0 = qt*64 + w*16;
  const int fr = l&15, fs = l>>4;
  const int srow = l>>3, sslot = (l&7)^srow;
  bf16x8 qf0 = *(const bf16x8*)&Qb[(size_t)(q0+fr)*64 + fs*8];
  bf16x8 qf1 = *(const bf16x8*)&Qb[(size_t)(q0+fr)*64 + 32 + fs*8];
  f32x4 o[4];
  float lsum[4];
  #pragma unroll
  for(int n=0;n<4;n++){
    #pragma unroll
    for(int e=0;e<4;e++) o[n][e]=0.f;
  }
  #pragma unroll
  for(int r=0;r<4;r++) lsum[r]=0.f;
  auto stage=[&](int buf,int k0){
    #pragma unroll
    for(int c=0;c<2;c++)
      gload_lds16(Kb + (size_t)(k0 + c*32 + w*8 + srow)*64 + sslot*8,
                  &Ks[buf][(c*32 + w*8)*64]);
    #pragma unroll
    for(int c=0;c<2;c++)
      gload_lds16(Vb + (size_t)(c*32 + w*8 + srow)*1024 + k0 + sslot*8,
                  &Vs[buf][(c*32 + w*8)*64]);
  };
  stage(0,0);
  for(int t=0;t<8;t++){
    const int cur = t&1;
    if(t<7){
      stage(cur^1,(t+1)*64);
      waitcnt_vm<4>();
    } else {
      waitcnt_vm<0>();
    }
    __builtin_amdgcn_s_barrier();
    f32x4 s[4];
    #pragma unroll
    for(int g=0;g<4;g++){
      #pragma unroll
      for(int e=0;e<4;e++) s[g][e]=0.f;
      int kr = g*16 + fr;
      bf16x8 kfa = *(const bf16x8*)&Ks[cur][kr*64 + ((fs  )^(kr&7))*8];
      bf16x8 kfb = *(const bf16x8*)&Ks[cur][kr*64 + ((4+fs)^(kr&7))*8];
      s[g] = __builtin_amdgcn_mfma_f32_16x16x32_bf16(qf0, kfa, s[g], 0,0,0);
      s[g] = __builtin_amdgcn_mfma_f32_16x16x32_bf16(qf1, kfb, s[g], 0,0,0);
    }
    #pragma unroll
    for(int g=0;g<4;g++){
      #pragma unroll
      for(int r=0;r<4;r++){
        float p = exp2f(fminf(s[g][r]*0.18033688011112042f, 86.f));
        lsum[r] += p;
        Plds[w][fs*4+r][g*16+fr] = f2bf(p);
      }
    }
    bf16x8 pa0 = *(const bf16x8*)&Plds[w][fr][fs*8];
    bf16x8 pa1 = *(const bf16x8*)&Plds[w][fr][32 + fs*8];
    #pragma unroll
    for(int n=0;n<4;n++){
      int vr = n*16 + fr;
      bf16x8 vf0 = *(const bf16x8*)&Vs[cur][vr*64 + ((fs  )^(vr&7))*8];
      bf16x8 vf1 = *(const bf16x8*)&Vs[cur][vr*64 + ((4+fs)^(vr&7))*8];
      o[n] = __builtin_amdgcn_mfma_f32_16x16x32_bf16(pa0, vf0, o[n], 0,0,0);
      o[n] = __builtin_amdgcn_mfma_f32_16x16x32_bf16(pa1, vf1, o[n], 0,0,0);
    }
    __builtin_amdgcn_s_barrier();
  }
  #pragma unroll
  for(int r=0;r<4;r++){
    float srw = lsum[r];
    #pragma unroll
    for(int dd=1; dd<16; dd<<=1) srw += __shfl_xor(srw,dd,64);
    int q = q0 + fs*4 + r;
    if(fr==0) Lp[q] = srw;
    #pragma unroll
    for(int n=0;n<4;n++) Op[(size_t)q*64 + n*16 + fr] = o[n][r];
  }
}

// combine: ctx = (Op0+Op1)/(L0+L1) -> acb cols [1024,2048)
__global__ __launch_bounds__(256) void k_mha_comb(const float* __restrict__ Opart,
    const float* __restrict__ Lpart, ushortT* __restrict__ acb){
  int g = blockIdx.x*256 + threadIdx.x;
  size_t base = (size_t)g*8;
  int bh = (int)(base>>16); int rem = (int)(base&65535);
  int q = rem>>6, c = rem&63;
  const float* O0 = Opart + ((size_t)bh<<16);
  const float* O1 = Opart + ((size_t)(32+bh)<<16);
  float4 a0=*(const float4*)&O0[rem], a1=*(const float4*)&O0[rem+4];
  float4 b0=*(const float4*)&O1[rem], b1=*(const float4*)&O1[rem+4];
  float inv = 1.f/(Lpart[bh*1024+q] + Lpart[(32+bh)*1024+q]);
  float v0=(a0.x+b0.x)*inv, v1=(a0.y+b0.y)*inv, v2=(a0.z+b0.z)*inv, v3=(a0.w+b0.w)*inv;
  float v4=(a1.x+b1.x)*inv, v5=(a1.y+b1.y)*inv, v6=(a1.z+b1.z)*inv, v7=(a1.w+b1.w)*inv;
  int b_=bh>>4, h_=bh&15;
  uint4 u;
  u.x = (unsigned)f2bf(v0) | ((unsigned)f2bf(v1)<<16);
  u.y = (unsigned)f2bf(v2) | ((unsigned)f2bf(v3)<<16);
  u.z = (unsigned)f2bf(v4) | ((unsigned)f2bf(v5)<<16);
  u.w = (unsigned)f2bf(v6) | ((unsigned)f2bf(v7)<<16);
  *(uint4*)&acb[((size_t)(b_*1024+q))*2048 + 1024 + h_*64 + c] = u;
}

// top-k(8 of 64) -> softmax -> token_recipe[m,32]
__global__ void k_topk(const float* __restrict__ sc, const float* __restrict__ P,
                       float* __restrict__ tr){
  int m = blockIdx.x*blockDim.x + threadIdx.x;
  if(m>=M_) return;
  float s[NN_];
  #pragma unroll
  for(int i=0;i<NN_;i++) s[i]=sc[m*NN_+i];
  int idx[KTOP_]; float val[KTOP_];
  unsigned long long used=0ull;
  #pragma unroll
  for(int kk=0;kk<KTOP_;kk++){
    float best=-3.4e38f; int bi=0;
    #pragma unroll
    for(int i=0;i<NN_;i++){
      bool free_ = !((used>>i)&1ull);
      if(free_ && s[i]>best){ best=s[i]; bi=i; }
    }
    used |= (1ull<<bi); idx[kk]=bi; val[kk]=best;
  }
  float m0=val[0], sum=0.f; float w[KTOP_];
  #pragma unroll
  for(int kk=0;kk<KTOP_;kk++){ w[kk]=expf(val[kk]-m0); sum+=w[kk]; }
  float inv=1.f/sum;
  float out[NB_];
  #pragma unroll
  for(int j=0;j<NB_;j++) out[j]=0.f;
  #pragma unroll
  for(int kk=0;kk<KTOP_;kk++){
    float wk=w[kk]*inv; const float* pr = P + idx[kk]*NB_;
    #pragma unroll
    for(int j=0;j<NB_;j++) out[j] += wk*pr[j];
  }
  #pragma unroll
  for(int j=0;j<NB_;j++) tr[m*NB_+j]=out[j];
}

// fused: h[r] = sum_n tr[n]*Tb[m][n*64+r];  Gb[m][n*64+r] = bf16(tr[n]*h[r])
__global__ __launch_bounds__(256) void k_hG(const ushortT* __restrict__ Tb,
    const float* __restrict__ tr, ushortT* __restrict__ Gb){
  int mi = threadIdx.x>>6, r = threadIdx.x&63;
  int m = blockIdx.x*4 + mi;
  __shared__ float t32[4][NB_];
  if(r<NB_) t32[mi][r]=tr[m*NB_+r];
  __syncthreads();
  float h=0.f;
  #pragma unroll
  for(int n=0;n<NB_;n++) h += t32[mi][n]*bf2f(Tb[(size_t)m*2048 + n*64 + r]);
  #pragma unroll
  for(int n=0;n<NB_;n++) Gb[(size_t)m*2048 + n*64 + r] = f2bf(t32[mi][n]*h);
}

// ---------------- launch ----------------
template<int BM,int BN,int OUT,int EPI>
static void mgemm(hipStream_t st, const ushortT*A,int lda,int K,const ushortT*Wt,
                  void*C,int N,const float*bias,const float*res,
                  const ushortT*res16,const float*alphaP,ushortT*qkv,int M){
  dim3 g(N/BN, M/BM), blk(256);
  k_mgemm<BM,BN,OUT,EPI><<<g,blk,0,st>>>(A,lda,K,Wt,C,N,bias,res,res16,alphaP,qkv);
}

extern "C" void kernel_launch(void* const* d_in, const int* in_sizes, int n_in,
                              void* d_out, int out_size, void* d_ws, size_t ws_size,
                              hipStream_t stream){
  (void)in_sizes; (void)n_in; (void)out_size; (void)ws_size;
  const float* x    = (const float*)d_in[0];
  const float* rec  = (const float*)d_in[1];
  const float* bemb = (const float*)d_in[2];
  const float* bA   = (const float*)d_in[3];
  const float* wq   = (const float*)d_in[4];  const float* bq = (const float*)d_in[5];
  const float* wk   = (const float*)d_in[6];  const float* bk = (const float*)d_in[7];
  const float* wv   = (const float*)d_in[8];  const float* bv = (const float*)d_in[9];
  const float* wsm  = (const float*)d_in[10]; const float* bs = (const float*)d_in[11];
  const float* wup  = (const float*)d_in[12]; const float* bup= (const float*)d_in[13];
  const float* wdn  = (const float*)d_in[14]; const float* bdn= (const float*)d_in[15];
  const float* alpha= (const float*)d_in[16];
  const float* g1   = (const float*)d_in[17]; const float* be1= (const float*)d_in[18];
  const float* g2   = (const float*)d_in[19]; const float* be2= (const float*)d_in[20];
  float* out = (float*)d_out;
  char* wsb = (char*)d_ws;
  const size_t MB = 1u<<20;
  ushortT* acb   = (ushortT*)(wsb + 0*MB);    // [2048][2048] bf16: xn1 | ctx
  ushortT* xn2b  = (ushortT*)(wsb + 8*MB);    // [2048][1024] bf16 (xn2 -> x_filt in place)
  ushortT* qkv   = (ushortT*)(wsb + 20*MB);   // Qh(2M) Kh(2M) Vt(2M) ushorts
  ushortT* Gb    = qkv;                        // overlay (8MB) after attn
  float*   Lpart = (float*)  (wsb + 32*MB);   // free outside attention
  ushortT* Tb    = (ushortT*)(wsb + 40*MB);   // [2048][2048] bf16
  float*   Opart = (float*)  (wsb + 40*MB);   // overlay: free during attention (16MB)
  ushortT* hidb  = (ushortT*)(wsb + 40*MB);   // overlay after k_hG: [2048][4096] bf16
  ushortT* wqkvt = (ushortT*)(wsb + 56*MB);   // [3072][1024]
  ushortT* wsb16 = (ushortT*)(wsb + 62*MB);   // ws straight bf16 [2048][1024]
  ushortT* wupt  = (ushortT*)(wsb + 66*MB);   // [4096][1024]
  ushortT* wdnt  = (ushortT*)(wsb + 74*MB);   // [1024][4096]
  ushortT* Abnr  = (ushortT*)(wsb + 82*MB);   // [2048][1024]
  ushortT* Abdnr = (ushortT*)(wsb + 86*MB);   // [1024][2048]
  float*   bqkv  = (float*)  (wsb + 90*MB);   // 3072
  float*   P     = bqkv + 4096;               // 2048
  float*   trp   = P + 2048;                  // 65536
  float*   nsc   = trp + 65536;               // 131072
  float*   sbias = nsc + 131072;              // 64
  ushortT* embb  = (ushortT*)(wsb + 92*MB);   // [64][1024] bf16
  ushortT* wseb  = embb + 65536;              // [64][2048] bf16

  // ---- weight conversion ----
  k_cvt_qkv<<<dim3(32,32,3),256,0,stream>>>(wq,wk,wv, wqkvt);
  k_cvt_str<<<2048,256,0,stream>>>(wsm, wsb16);
  k_cvt_wt<<<dim3(128,32),256,0,stream>>>(wup, wupt, 1024, 4096);
  k_cvt_wt<<<dim3(32,128),256,0,stream>>>(wdn, wdnt, 4096, 1024);
  k_cat3<<<12,256,0,stream>>>(bq,bk,bv,bqkv);
  k_cvt_basis<<<dim3(32,2,32),256,0,stream>>>(bA, Abnr, Abdnr);

  // ---- router ----
  k_softmax_recipe<<<1,64,0,stream>>>(rec,P);
  k_neuron_emb<<<NN_,256,0,stream>>>(P,bemb,bs,embb,sbias);
  // wseb[64][2048] = emb @ ws^T  (268 MF)
  mgemm<64,64,1,0>(stream, embb,1024,1024, wsb16, wseb,2048, nullptr,nullptr,nullptr,nullptr, nullptr, 64);
  k_ln_dual<<<M_,256,0,stream>>>(x,g1,be1,g2,be2,acb,xn2b);
  mgemm<128,64,2,0>(stream, acb,2048,1024, wqkvt, nullptr,3072, bqkv,nullptr,nullptr,nullptr, qkv, M_);
  k_mha<<<dim3(16,H_,4),256,0,stream>>>(qkv, qkv+2097152, qkv+4194304, Opart, Lpart);
  k_mha_comb<<<1024,256,0,stream>>>(Opart, Lpart, acb);
  // scores[2048][64] = cat @ wseb^T + sbias   (537 MF)
  mgemm<64,64,0,0>(stream, acb,2048,2048, wseb, nsc,64, sbias,nullptr,nullptr,nullptr, nullptr, M_);
  k_topk<<<M_/256,256,0,stream>>>(nsc,P,trp);

  // ---- basis FFN ----
  mgemm<128,64,1,0>(stream, xn2b,1024,1024, Abnr, Tb,2048, nullptr,nullptr,nullptr,nullptr, nullptr, M_);
  k_hG<<<512,256,0,stream>>>(Tb,trp,Gb);
  mgemm<64,64,1,3>(stream, Gb,2048,2048, Abdnr, xn2b,1024, nullptr,nullptr,xn2b,alpha, nullptr, M_);
  mgemm<128,128,1,1>(stream, xn2b,1024,1024, wupt, hidb,4096, bup,nullptr,nullptr,nullptr, nullptr, M_);
  mgemm<64,64,0,2>(stream, hidb,4096,4096, wdnt, out,1024, bdn,x,nullptr,nullptr, nullptr, M_);
}